// Round 2
// baseline (127.782 us; speedup 1.0000x reference)
//
#include <hip/hip_runtime.h>

#define NIMG 16
#define H 512
#define W 512
#define HALF 7        // PATCH=15

// ---- fused-tile geometry (64x128 output tile) ----
#define RT 64         // output rows per tile (full res)
#define CT 128        // output cols per tile (full res)
#define YROWS 78      // RT + 2*HALF
#define YCOLS 144     // CT + 16 (halo 8 each side, float4-aligned stage-1 stores)
#define YSTR 148      // sY stride (floats): %4==0 (float4), %32==20 -> period-8 bank spread
#define CROWS 46      // RT/2 + 2*HALF
#define CSTR 88       // sU/sV stride (ushorts): 176B, %16==0, 44 banks %32=12 -> period-8
#define NPAIR (CROWS * 40)   // stage-1 tasks: 46 rows x 40 col-pairs (4-px wide) = 1840

// bf16 helpers (RNE), bit-level.
static __device__ __forceinline__ unsigned short f2bf(float f) {
    unsigned u = __float_as_uint(f);
    u += 0x7FFFu + ((u >> 16) & 1u);
    return (unsigned short)(u >> 16);
}
static __device__ __forceinline__ float bf2f(unsigned short h) {
    return __uint_as_float(((unsigned)h) << 16);
}
static __device__ __forceinline__ float bflo(unsigned v) {
    return __uint_as_float(v << 16);
}
static __device__ __forceinline__ float bfhi(unsigned v) {
    return __uint_as_float(v & 0xFFFF0000u);
}
static __device__ __forceinline__ unsigned pack2bf(float lo, float hi) {
    return (unsigned)f2bf(lo) | ((unsigned)f2bf(hi) << 16);
}

// ---------------------------------------------------------------------------
// Fused: diff -> YUV -> 2x2 pool -> 15x15 box (vbox in-place, hbox in regs)
// -> square -> per-block partial. One block per 64x128 output tile.
// Grid: 16 img * 8 row-tiles * 4 col-tiles = 512 blocks -> 2 blocks/CU.
// LDS: fp32 dY[78][148] + bf16 dU/dV[46][88] = 62.4 KiB -> 2 blocks/CU fit.
// __launch_bounds__(512,4): cap VGPR<=128 so 16 waves/CU materialize.
// ---------------------------------------------------------------------------
__global__ __launch_bounds__(512, 4) void fused_loss_kernel(
        const float* __restrict__ in, const float* __restrict__ tgt,
        float invY, float invC, float* __restrict__ partials) {
    __shared__ float sY[YROWS * YSTR];
    __shared__ unsigned short sU[CROWS * CSTR];
    __shared__ unsigned short sV[CROWS * CSTR];
    __shared__ float part[8];

    const int tid = threadIdx.x;
    const int b = blockIdx.x;
    const int n  = b >> 5;
    const int rt = (b >> 2) & 7;
    const int ct = b & 3;
    const int r0 = rt << 6;   // first output row (full res)
    const int c0 = ct << 7;   // first output col (full res)

    const size_t plane = (size_t)H * W;
    const float* pi = in  + (size_t)n * 3 * plane;
    const float* pt = tgt + (size_t)n * 3 * plane;

    // ---- Stage 1: 4x2-pixel patch-pairs -> dY fp32 + two pooled dU/dV bf16.
    // Pair q covers full-res cols xx=c0-16+4q (float4-aligned), rows yy,yy+1.
    // Out-of-image regions contribute zeros (= the conv's zero padding).
    // Luma LDS col 0 <-> global col c0-8; row 0 <-> global row r0-7.
    // Chroma LDS col 0 <-> pooled col c0/2-8; row 0 <-> pooled row r0/2-7.
#pragma unroll 2
    for (int i = tid; i < NPAIR; i += 512) {
        const int pr = i / 40;
        const int q  = i - pr * 40;
        const int yy = r0 - 14 + 2 * pr;
        const int xx = c0 - 16 + 4 * q;

        float4 dr0 = make_float4(0.f, 0.f, 0.f, 0.f), dr1 = dr0;
        float4 dg0 = dr0, dg1 = dr0, db0 = dr0, db1 = dr0;

        if ((unsigned)yy < H && (unsigned)xx < W) {   // 4-aligned -> fully in/out
            const size_t off = (size_t)yy * W + xx;
            float4 a, t;
            a = *(const float4*)(pi + off);              t = *(const float4*)(pt + off);
            dr0 = make_float4(a.x - t.x, a.y - t.y, a.z - t.z, a.w - t.w);
            a = *(const float4*)(pi + off + W);          t = *(const float4*)(pt + off + W);
            dr1 = make_float4(a.x - t.x, a.y - t.y, a.z - t.z, a.w - t.w);
            a = *(const float4*)(pi + plane + off);      t = *(const float4*)(pt + plane + off);
            dg0 = make_float4(a.x - t.x, a.y - t.y, a.z - t.z, a.w - t.w);
            a = *(const float4*)(pi + plane + off + W);  t = *(const float4*)(pt + plane + off + W);
            dg1 = make_float4(a.x - t.x, a.y - t.y, a.z - t.z, a.w - t.w);
            a = *(const float4*)(pi + 2*plane + off);    t = *(const float4*)(pt + 2*plane + off);
            db0 = make_float4(a.x - t.x, a.y - t.y, a.z - t.z, a.w - t.w);
            a = *(const float4*)(pi + 2*plane + off + W);t = *(const float4*)(pt + 2*plane + off + W);
            db1 = make_float4(a.x - t.x, a.y - t.y, a.z - t.z, a.w - t.w);
        }

        // luma diffs (8 pixels)
        float4 y0, y1;
        y0.x = 0.299f*dr0.x + 0.587f*dg0.x + 0.114f*db0.x;
        y0.y = 0.299f*dr0.y + 0.587f*dg0.y + 0.114f*db0.y;
        y0.z = 0.299f*dr0.z + 0.587f*dg0.z + 0.114f*db0.z;
        y0.w = 0.299f*dr0.w + 0.587f*dg0.w + 0.114f*db0.w;
        y1.x = 0.299f*dr1.x + 0.587f*dg1.x + 0.114f*db1.x;
        y1.y = 0.299f*dr1.y + 0.587f*dg1.y + 0.114f*db1.y;
        y1.z = 0.299f*dr1.z + 0.587f*dg1.z + 0.114f*db1.z;
        y1.w = 0.299f*dr1.w + 0.587f*dg1.w + 0.114f*db1.w;

        const int ly0 = 2 * pr - 7;
        const int lx  = 4 * q - 8;
        if ((unsigned)lx < YCOLS) {
            if ((unsigned)ly0 < YROWS)
                *(float4*)&sY[ly0 * YSTR + lx] = y0;
            if ((unsigned)(ly0 + 1) < YROWS)
                *(float4*)&sY[(ly0 + 1) * YSTR + lx] = y1;
        }

        // pooled chroma (two 2x2 patches; +128 cancels in input-target)
        const float srA = dr0.x + dr0.y + dr1.x + dr1.y;
        const float sgA = dg0.x + dg0.y + dg1.x + dg1.y;
        const float sbA = db0.x + db0.y + db1.x + db1.y;
        const float srB = dr0.z + dr0.w + dr1.z + dr1.w;
        const float sgB = dg0.z + dg0.w + dg1.z + dg1.w;
        const float sbB = db0.z + db0.w + db1.z + db1.w;
        const float uA = (-0.169f*srA - 0.331f*sgA + 0.5f *sbA) * 0.25f;
        const float vA = ( 0.5f  *srA - 0.46f *sgA - 0.04f*sbA) * 0.25f;
        const float uB = (-0.169f*srB - 0.331f*sgB + 0.5f *sbB) * 0.25f;
        const float vB = ( 0.5f  *srB - 0.46f *sgB - 0.04f*sbB) * 0.25f;
        *(unsigned*)&sU[pr * CSTR + 2 * q] = pack2bf(uA, uB);
        *(unsigned*)&sV[pr * CSTR + 2 * q] = pack2bf(vA, vB);
    }
    __syncthreads();

    // ---- Phase A: vertical 15-tap box, in-place (one thread per column).
    // Row y of the window dies exactly when output y is produced -> overwrite.
    // 144 luma cols + 2*80 chroma cols = 304 tasks.
    if (tid < 304) {
        if (tid < YCOLS) {
            const int j = tid;
            float s = 0.f;
#pragma unroll
            for (int r = 0; r < 14; ++r) s += sY[r * YSTR + j];
#pragma unroll
            for (int y = 0; y < RT; ++y) {
                s += sY[(y + 14) * YSTR + j];
                const float o = s;
                s -= sY[y * YSTR + j];
                sY[y * YSTR + j] = o;
            }
        } else {
            const int jj = tid - YCOLS;
            unsigned short* sp = (jj < 80) ? sU : sV;
            const int j = (jj < 80) ? jj : jj - 80;
            float s = 0.f;
#pragma unroll
            for (int r = 0; r < 14; ++r) s += bf2f(sp[r * CSTR + j]);
#pragma unroll
            for (int y = 0; y < RT / 2; ++y) {
                s += bf2f(sp[(y + 14) * CSTR + j]);
                const float o = s;
                s -= bf2f(sp[y * CSTR + j]);
                sp[y * CSTR + j] = f2bf(o);
            }
        }
    }
    __syncthreads();

    // ---- Phase B: horizontal 15-tap box + square, sliding in registers.
    float accY = 0.f, accC = 0.f;
    const int wv = tid >> 6, lane = tid & 63;

    {   // luma: wave wv owns 16-col segment, lane = output row (0..63)
        float wn[32];
        const int base = lane * YSTR + (wv << 4);
#pragma unroll
        for (int j = 0; j < 8; ++j)
            *(float4*)&wn[4 * j] = *(const float4*)&sY[base + 4 * j];
        // out col xo = 16*wv + k  <->  window wn[k+1 .. k+15]
        float s = 0.f;
#pragma unroll
        for (int j = 1; j <= 14; ++j) s += wn[j];
#pragma unroll
        for (int k = 0; k < 16; ++k) {
            s += wn[15 + k];
            accY += s * s;
            s -= wn[1 + k];
        }
    }

    {   // chroma: lane>>5 = plane, lane&31 = row, wave = 8-col segment
        const int pl = lane >> 5, y = lane & 31;
        const unsigned short* sp = pl ? sV : sU;
        const int base = y * CSTR + (wv << 3);
        float wn[24];
#pragma unroll
        for (int j = 0; j < 3; ++j) {
            const uint4 v = *(const uint4*)&sp[base + 8 * j];
            wn[8 * j + 0] = bflo(v.x); wn[8 * j + 1] = bfhi(v.x);
            wn[8 * j + 2] = bflo(v.y); wn[8 * j + 3] = bfhi(v.y);
            wn[8 * j + 4] = bflo(v.z); wn[8 * j + 5] = bfhi(v.z);
            wn[8 * j + 6] = bflo(v.w); wn[8 * j + 7] = bfhi(v.w);
        }
        // out col xo = 8*wv + k  <->  window wn[k+1 .. k+15]
        float s = 0.f;
#pragma unroll
        for (int j = 1; j <= 14; ++j) s += wn[j];
#pragma unroll
        for (int k = 0; k < 8; ++k) {
            s += wn[15 + k];
            accC += s * s;
            s -= wn[1 + k];
        }
    }

    // ---- block reduction -> one partial per block
    float v = accY * invY + accC * invC;
    for (int o = 32; o > 0; o >>= 1) v += __shfl_down(v, o, 64);
    if (lane == 0) part[wv] = v;
    __syncthreads();
    if (tid == 0) {
        float s = 0.f;
#pragma unroll
        for (int j = 0; j < 8; ++j) s += part[j];
        partials[b] = s;
    }
}

// ---------------------------------------------------------------------------
// Final: single-block sum of 512 partials -> out[0].
// ---------------------------------------------------------------------------
__global__ void final_reduce_kernel(const float* __restrict__ partials, int n,
                                    float* __restrict__ out) {
    float s = 0.f;
    for (int i = threadIdx.x; i < n; i += 256) s += partials[i];
    for (int o = 32; o > 0; o >>= 1) s += __shfl_down(s, o, 64);
    __shared__ float part[4];
    const int lane = threadIdx.x & 63, wid = threadIdx.x >> 6;
    if (lane == 0) part[wid] = s;
    __syncthreads();
    if (threadIdx.x == 0)
        *out = part[0] + part[1] + part[2] + part[3];
}

extern "C" void kernel_launch(void* const* d_in, const int* in_sizes, int n_in,
                              void* d_out, int out_size, void* d_ws, size_t ws_size,
                              hipStream_t stream) {
    const float* input  = (const float*)d_in[0];
    const float* target = (const float*)d_in[1];
    float* out = (float*)d_out;
    float* partials = (float*)d_ws;   // 512 floats

    const float invY = 1.0f / (float)((size_t)NIMG * H * W);            // 1/4194304
    const float invC = 1.0f / (float)((size_t)NIMG * (H/2) * (W/2));    // 1/1048576

    fused_loss_kernel<<<NIMG * 8 * 4, 512, 0, stream>>>(input, target, invY, invC, partials);
    final_reduce_kernel<<<1, 256, 0, stream>>>(partials, NIMG * 8 * 4, out);
}